// Round 6
// baseline (422.417 us; speedup 1.0000x reference)
//
#include <hip/hip_runtime.h>
#include <math.h>

#define N0 100000
#define N1 20000
#define N2 4000
#define HDIM 128
#define E0C 1600000
#define E1C 320000
#define E2C 64000
#define EPSBN 1e-5f

typedef unsigned int u32;
typedef float f32x4 __attribute__((ext_vector_type(4)));
typedef short bf16x8 __attribute__((ext_vector_type(8)));

union FragU { uint4 u; bf16x8 h; };
__device__ __forceinline__ bf16x8 asbf(uint4 v) { FragU x; x.u = v; return x.h; }

__device__ __forceinline__ float bl(u32 p) { return __uint_as_float(p << 16); }
__device__ __forceinline__ float bh(u32 p) { return __uint_as_float(p & 0xFFFF0000u); }
__device__ __forceinline__ u32 pack2(float a, float b) {
    u32 ua = __float_as_uint(a), ub = __float_as_uint(b);
    ua = (ua + 0x7FFFu + ((ua >> 16) & 1u)) >> 16;
    ub = (ub + 0x7FFFu + ((ub >> 16) & 1u)) >> 16;
    return ua | (ub << 16);
}

// concatenated destination space
#define OFF0 0
#define OFF1 (N0)
#define OFF2 (N0 + N1)
#define OFF3 (N0 + N1 + N2)
#define OFF4 (N0 + N1 + N2 + N1)
#define OFFT (N0 + N1 + N2 + N1 + N2)        // 148000

// concatenated work items
#define S0 (E0C)
#define S1 (E0C + E1C)
#define S2 (E0C + E1C + E2C)
#define S3 (E0C + E1C + E2C + N0)
#define S4 (E0C + E1C + E2C + N0 + N1)       // 2,104,000

// counting-sort geometry
#define NBUCK ((OFFT + 1023) / 1024)         // 145 coarse buckets
#define ITEMS_PER_BLK 2048
#define NBA ((S4 + ITEMS_PER_BLK - 1) / ITEMS_PER_BLK)   // 1028 blocks
#define BH_N (NBUCK * NBA)
#define NBLK2 ((BH_N + 1023) / 1024)

#define NWMAT 9   // W0,W1,W2,W3lo,W3hi,pW0..3 packed matrices

// ---------------- CSR build (LDS counting sort, zero global atomics) ----------------
// binPair entry: (concat&1023)<<17 | payload   (payload < 2^17, bucket implied by position)

__device__ __forceinline__ void item_full(int g,
    const int* __restrict__ ei0r, const int* __restrict__ ei0c,
    const int* __restrict__ ei1r, const int* __restrict__ ei1c,
    const int* __restrict__ ei2r, const int* __restrict__ ei2c,
    const int* __restrict__ p1, const int* __restrict__ p2,
    int& concat, int& payload)
{
    if (g < S0)      { concat = ei0c[g];             payload = ei0r[g]; }
    else if (g < S1) { int i = g - S0; concat = OFF1 + ei1c[i]; payload = ei1r[i]; }
    else if (g < S2) { int i = g - S1; concat = OFF2 + ei2c[i]; payload = ei2r[i]; }
    else if (g < S3) { int i = g - S2; concat = OFF3 + p1[i];   payload = i; }
    else             { int i = g - S3; concat = OFF4 + p2[i];   payload = i; }
}

__device__ __forceinline__ int item_concat(int g,
    const int* __restrict__ ei0c, const int* __restrict__ ei1c, const int* __restrict__ ei2c,
    const int* __restrict__ p1, const int* __restrict__ p2)
{
    if (g < S0)      return ei0c[g];
    else if (g < S1) return OFF1 + ei1c[g - S0];
    else if (g < S2) return OFF2 + ei2c[g - S1];
    else if (g < S3) return OFF3 + p1[g - S2];
    else             return OFF4 + p2[g - S3];
}

// binhist + W prepack merged: blocks [0,NBA) histogram, [NBA,NBA+9) pack weights.
__global__ __launch_bounds__(256) void binhist_kernel(
    const int* __restrict__ ei0c, const int* __restrict__ ei1c, const int* __restrict__ ei2c,
    const int* __restrict__ p1, const int* __restrict__ p2,
    int* __restrict__ blockHist,
    const float* __restrict__ W0p, const float* __restrict__ W1p,
    const float* __restrict__ W2p, const float* __restrict__ W3p,
    const float* __restrict__ pWp, u32* __restrict__ Wpk)
{
    __shared__ int hist[NBUCK];
    int tid = threadIdx.x, blk = blockIdx.x;
    if (blk >= NBA) {
        int b = blk - NBA;
        const float* src;
        if (b == 0) src = W0p;
        else if (b == 1) src = W1p;
        else if (b == 2) src = W2p;
        else if (b == 3) src = W3p;
        else if (b == 4) src = W3p + 128 * 128;
        else src = pWp + (b - 5) * 128 * 128;
        u32* dst = Wpk + b * 8192;
        #pragma unroll
        for (int it = 0; it < 32; it++) {
            int flat = it * 256 + tid;
            int i = flat & 3;
            int ln = (flat >> 2) & 63;
            int s = (flat >> 8) & 3;
            int t = flat >> 10;
            int mm = ln & 15, qq = ln >> 4;
            int k0 = s * 32 + qq * 8 + 2 * i;
            int col = t * 16 + mm;
            dst[flat] = pack2(src[k0 * 128 + col], src[(k0 + 1) * 128 + col]);
        }
        return;
    }
    for (int i = tid; i < NBUCK; i += 256) hist[i] = 0;
    __syncthreads();
    int base = blk * ITEMS_PER_BLK;
    #pragma unroll
    for (int k = 0; k < ITEMS_PER_BLK / 256; k++) {
        int g = base + k * 256 + tid;
        if (g < S4) {
            int c = item_concat(g, ei0c, ei1c, ei2c, p1, p2);
            atomicAdd(&hist[c >> 10], 1);
        }
    }
    __syncthreads();
    for (int b = tid; b < NBUCK; b += 256) blockHist[b * NBA + blk] = hist[b];
}

__global__ __launch_bounds__(256) void scan_k1(const int* __restrict__ c, int* __restrict__ bsum, int n) {
    int t = threadIdx.x;
    int base = blockIdx.x * 1024 + t * 4;
    int s = 0;
    #pragma unroll
    for (int j = 0; j < 4; j++) {
        int idx = base + j;
        if (idx < n) s += c[idx];
    }
    #pragma unroll
    for (int o = 32; o > 0; o >>= 1) s += __shfl_down(s, o, 64);
    __shared__ int ws[4];
    if ((t & 63) == 0) ws[t >> 6] = s;
    __syncthreads();
    if (t == 0) bsum[blockIdx.x] = ws[0] + ws[1] + ws[2] + ws[3];
}

// scan_k2 + folded bn_pre (512 scale/shift elems, 2 per thread)
__global__ __launch_bounds__(256) void scan_k2(int* __restrict__ bsum, int* __restrict__ totalOut, int nb,
    const float* __restrict__ g, const float* __restrict__ beta,
    const float* __restrict__ mean, const float* __restrict__ var,
    float* __restrict__ scale, float* __restrict__ shift)
{
    int t = threadIdx.x;
    #pragma unroll
    for (int j = 0; j < 2; j++) {
        int i = j * 256 + t;
        float s = g[i] * rsqrtf(var[i] + EPSBN);
        scale[i] = s;
        shift[i] = beta[i] - mean[i] * s;
    }
    int v = (t < nb) ? bsum[t] : 0;
    __shared__ int ts[256];
    ts[t] = v;
    __syncthreads();
    for (int o = 1; o < 256; o <<= 1) {
        int u = (t >= o) ? ts[t - o] : 0;
        __syncthreads();
        ts[t] += u;
        __syncthreads();
    }
    if (t < nb) bsum[t] = ts[t] - v;
    if (t == nb - 1) *totalOut = ts[t];
}

__global__ __launch_bounds__(256) void scan_k3(const int* __restrict__ c, const int* __restrict__ bsum,
                                               const int* __restrict__ total,
                                               int* __restrict__ S, int n) {
    int t = threadIdx.x;
    int base = blockIdx.x * 1024 + t * 4;
    int v[4];
    #pragma unroll
    for (int j = 0; j < 4; j++) v[j] = (base + j < n) ? c[base + j] : 0;
    int tsum = v[0] + v[1] + v[2] + v[3];
    __shared__ int ts[256];
    ts[t] = tsum;
    __syncthreads();
    for (int o = 1; o < 256; o <<= 1) {
        int u = (t >= o) ? ts[t - o] : 0;
        __syncthreads();
        ts[t] += u;
        __syncthreads();
    }
    int run = bsum[blockIdx.x] + ts[t] - tsum;
    #pragma unroll
    for (int j = 0; j < 4; j++) {
        if (base + j < n) { S[base + j] = run; run += v[j]; }
    }
    if (blockIdx.x == 0 && t == 0) S[n] = *total;
}

__global__ __launch_bounds__(256) void binfill_kernel(
    const int* __restrict__ ei0r, const int* __restrict__ ei0c,
    const int* __restrict__ ei1r, const int* __restrict__ ei1c,
    const int* __restrict__ ei2r, const int* __restrict__ ei2c,
    const int* __restrict__ p1, const int* __restrict__ p2,
    const int* __restrict__ OfsAbs, u32* __restrict__ binPair)
{
    __shared__ int cur[NBUCK];
    int tid = threadIdx.x, blk = blockIdx.x;
    for (int i = tid; i < NBUCK; i += 256) cur[i] = OfsAbs[i * NBA + blk];
    __syncthreads();
    int base = blk * ITEMS_PER_BLK;
    #pragma unroll
    for (int k = 0; k < ITEMS_PER_BLK / 256; k++) {
        int g = base + k * 256 + tid;
        if (g < S4) {
            int c, p;
            item_full(g, ei0r, ei0c, ei1r, ei1c, ei2r, ei2c, p1, p2, c, p);
            int pos = atomicAdd(&cur[c >> 10], 1);
            binPair[pos] = ((u32)(c & 1023) << 17) | (u32)p;
        }
    }
}

__global__ __launch_bounds__(1024) void bucket_build_kernel(
    const u32* __restrict__ binPair, const int* __restrict__ OfsAbs,
    int* __restrict__ rpAll, int* __restrict__ srcU,
    float* __restrict__ dis0, float* __restrict__ dis1, float* __restrict__ dis2)
{
    __shared__ int cnt_l[1024];
    __shared__ int rp_l[1024];
    __shared__ int wsum[16];
    int b = blockIdx.x, tid = threadIdx.x;
    int start = OfsAbs[b * NBA];
    int end = (b + 1 < NBUCK) ? OfsAbs[(b + 1) * NBA] : S4;
    int d0 = b << 10;
    int nd = OFFT - d0; if (nd > 1024) nd = 1024;

    cnt_l[tid] = 0;
    __syncthreads();
    for (int i = start + tid; i < end; i += 1024) {
        u32 e = binPair[i];
        atomicAdd(&cnt_l[e >> 17], 1);
    }
    __syncthreads();
    int v = cnt_l[tid];
    int lane = tid & 63, wv = tid >> 6;
    int s = v;
    #pragma unroll
    for (int o = 1; o < 64; o <<= 1) {
        int u = __shfl_up(s, o, 64);
        if (lane >= o) s += u;
    }
    if (lane == 63) wsum[wv] = s;
    __syncthreads();
    if (wv == 0) {
        int t2 = (lane < 16) ? wsum[lane] : 0;
        #pragma unroll
        for (int o = 1; o < 16; o <<= 1) {
            int u = __shfl_up(t2, o, 64);
            if (lane >= o) t2 += u;
        }
        if (lane < 16) wsum[lane] = t2;
    }
    __syncthreads();
    int incl = s + (wv ? wsum[wv - 1] : 0);
    rp_l[tid] = incl - v;   // exclusive scan
    __syncthreads();
    if (tid < nd) {
        int g = d0 + tid;
        rpAll[g] = start + rp_l[tid];
        float dv = rsqrtf((float)(v + 1));
        if (g < OFF1) dis0[g] = dv;
        else if (g < OFF2) dis1[g - OFF1] = dv;
        else if (g < OFF3) dis2[g - OFF2] = dv;
    }
    if (b == NBUCK - 1 && tid == 0) rpAll[OFFT] = S4;
    __syncthreads();
    for (int i = start + tid; i < end; i += 1024) {
        u32 e = binPair[i];
        int pos = start + atomicAdd(&rp_l[e >> 17], 1);
        srcU[pos] = (int)(e & 0x1FFFFu);
    }
}

// ---------------- gather kernels (bf16 features, fp32 accumulate) ----------------

// E0 half-feature gather: yh = one half [n][32] u32 (64 features).
// One row per wave; half-wave (32 lanes) = one edge = one 128B line request.
// Wave-uniform loop bounds; predicated tail; shfl_xor(32) combine.
__global__ __launch_bounds__(256) void gather128h_kernel(
    const int* __restrict__ rp, const int* __restrict__ srcl,
    const u32* __restrict__ yh, const float* __restrict__ dis,
    const float* __restrict__ biasHalf, u32* __restrict__ hHalf, int n)
{
    int wid = (int)((blockIdx.x * 256 + threadIdx.x) >> 6);
    int lane = threadIdx.x & 63;
    if (wid >= n) return;
    int l32 = lane & 31;
    int epar = lane >> 5;
    u32 self = yh[(long long)wid * 32 + l32];
    float ax = (epar == 0) ? bl(self) : 0.f;
    float ay = (epar == 0) ? bh(self) : 0.f;
    int e0 = rp[wid], e1 = rp[wid + 1];
    int eb = e0;
    for (; eb + 7 < e1; eb += 8) {
        int i0 = eb + epar;
        int s0 = srcl[i0], s1 = srcl[i0 + 2], s2 = srcl[i0 + 4], s3 = srcl[i0 + 6];
        u32 p0 = yh[(long long)s0 * 32 + l32];
        u32 p1 = yh[(long long)s1 * 32 + l32];
        u32 p2 = yh[(long long)s2 * 32 + l32];
        u32 p3 = yh[(long long)s3 * 32 + l32];
        ax += (bl(p0) + bl(p1)) + (bl(p2) + bl(p3));
        ay += (bh(p0) + bh(p1)) + (bh(p2) + bh(p3));
    }
    for (; eb + 3 < e1; eb += 4) {
        int i0 = eb + epar;
        int s0 = srcl[i0], s1 = srcl[i0 + 2];
        u32 p0 = yh[(long long)s0 * 32 + l32];
        u32 p1 = yh[(long long)s1 * 32 + l32];
        ax += bl(p0) + bl(p1);
        ay += bh(p0) + bh(p1);
    }
    for (; eb < e1; eb += 2) {
        int ei = eb + epar;
        bool v = ei < e1;
        int si = v ? srcl[ei] : wid;
        u32 p = yh[(long long)si * 32 + l32];
        if (v) { ax += bl(p); ay += bh(p); }
    }
    ax += __shfl_xor(ax, 32, 64);
    ay += __shfl_xor(ay, 32, 64);
    if (epar == 0) {
        float d = dis[wid];
        float2 b = ((const float2*)biasHalf)[l32];
        float r0 = fmaxf(fmaf(d, ax, b.x), 0.f);
        float r1 = fmaxf(fmaf(d, ay, b.y), 0.f);
        hHalf[(long long)wid * 64 + l32] = pack2(r0, r1);
    }
}

#define G128_LOAD(sym, off) u32 sym = y[(long long)srcl[e + off] * 64 + lane]

__global__ __launch_bounds__(256) void gather128_kernel(
    const int* __restrict__ rp, const int* __restrict__ srcl,
    const u32* __restrict__ y, const float* __restrict__ dis,
    const float* __restrict__ bias, u32* __restrict__ h, int n)
{
    int wid = (int)((blockIdx.x * 256 + threadIdx.x) >> 6);
    int lane = threadIdx.x & 63;
    if (wid >= n) return;
    u32 self = y[(long long)wid * 64 + lane];
    float ax = bl(self), ay = bh(self);
    int e = rp[wid], e1 = rp[wid + 1];
    for (; e + 7 < e1; e += 8) {
        G128_LOAD(p0, 0); G128_LOAD(p1, 1); G128_LOAD(p2, 2); G128_LOAD(p3, 3);
        G128_LOAD(p4, 4); G128_LOAD(p5, 5); G128_LOAD(p6, 6); G128_LOAD(p7, 7);
        ax += ((bl(p0) + bl(p1)) + (bl(p2) + bl(p3))) + ((bl(p4) + bl(p5)) + (bl(p6) + bl(p7)));
        ay += ((bh(p0) + bh(p1)) + (bh(p2) + bh(p3))) + ((bh(p4) + bh(p5)) + (bh(p6) + bh(p7)));
    }
    if (e + 3 < e1) {
        G128_LOAD(p0, 0); G128_LOAD(p1, 1); G128_LOAD(p2, 2); G128_LOAD(p3, 3);
        ax += (bl(p0) + bl(p1)) + (bl(p2) + bl(p3));
        ay += (bh(p0) + bh(p1)) + (bh(p2) + bh(p3));
        e += 4;
    }
    if (e + 1 < e1) {
        G128_LOAD(p0, 0); G128_LOAD(p1, 1);
        ax += bl(p0) + bl(p1);
        ay += bh(p0) + bh(p1);
        e += 2;
    }
    if (e < e1) {
        G128_LOAD(p0, 0);
        ax += bl(p0); ay += bh(p0);
    }
    float d = dis[wid];
    float2 b = ((const float2*)bias)[lane];
    float r0 = fmaxf(fmaf(d, ax, b.x), 0.f);
    float r1 = fmaxf(fmaf(d, ay, b.y), 0.f);
    h[(long long)wid * 64 + lane] = pack2(r0, r1);
}

__global__ __launch_bounds__(256) void gather10_lsm_kernel(
    const int* __restrict__ rp, const int* __restrict__ srcl,
    const u32* __restrict__ y4, const float* __restrict__ dis,
    const float* __restrict__ bias, float* __restrict__ out, int n)
{
    int c = blockIdx.x * blockDim.x + threadIdx.x;
    if (c >= n) return;
    float acc[10];
    {
        long long base = (long long)c * 8;
        uint4 q = *(const uint4*)(y4 + base);
        u32 q4 = y4[base + 4];
        acc[0] = bl(q.x); acc[1] = bh(q.x);
        acc[2] = bl(q.y); acc[3] = bh(q.y);
        acc[4] = bl(q.z); acc[5] = bh(q.z);
        acc[6] = bl(q.w); acc[7] = bh(q.w);
        acc[8] = bl(q4);  acc[9] = bh(q4);
    }
    int e = rp[c], e1 = rp[c + 1];
    for (; e + 3 < e1; e += 4) {
        long long bA = (long long)srcl[e] * 8;
        long long bB = (long long)srcl[e + 1] * 8;
        long long bC = (long long)srcl[e + 2] * 8;
        long long bD = (long long)srcl[e + 3] * 8;
        uint4 qa = *(const uint4*)(y4 + bA); u32 qa4 = y4[bA + 4];
        uint4 qb = *(const uint4*)(y4 + bB); u32 qb4 = y4[bB + 4];
        uint4 qc = *(const uint4*)(y4 + bC); u32 qc4 = y4[bC + 4];
        uint4 qd = *(const uint4*)(y4 + bD); u32 qd4 = y4[bD + 4];
        acc[0] += (bl(qa.x) + bl(qb.x)) + (bl(qc.x) + bl(qd.x));
        acc[1] += (bh(qa.x) + bh(qb.x)) + (bh(qc.x) + bh(qd.x));
        acc[2] += (bl(qa.y) + bl(qb.y)) + (bl(qc.y) + bl(qd.y));
        acc[3] += (bh(qa.y) + bh(qb.y)) + (bh(qc.y) + bh(qd.y));
        acc[4] += (bl(qa.z) + bl(qb.z)) + (bl(qc.z) + bl(qd.z));
        acc[5] += (bh(qa.z) + bh(qb.z)) + (bh(qc.z) + bh(qd.z));
        acc[6] += (bl(qa.w) + bl(qb.w)) + (bl(qc.w) + bl(qd.w));
        acc[7] += (bh(qa.w) + bh(qb.w)) + (bh(qc.w) + bh(qd.w));
        acc[8] += (bl(qa4) + bl(qb4)) + (bl(qc4) + bl(qd4));
        acc[9] += (bh(qa4) + bh(qb4)) + (bh(qc4) + bh(qd4));
    }
    for (; e < e1; e++) {
        long long bA = (long long)srcl[e] * 8;
        uint4 qa = *(const uint4*)(y4 + bA);
        u32 qa4 = y4[bA + 4];
        acc[0] += bl(qa.x); acc[1] += bh(qa.x);
        acc[2] += bl(qa.y); acc[3] += bh(qa.y);
        acc[4] += bl(qa.z); acc[5] += bh(qa.z);
        acc[6] += bl(qa.w); acc[7] += bh(qa.w);
        acc[8] += bl(qa4);  acc[9] += bh(qa4);
    }
    float d = dis[c];
    float m = -1e30f;
    #pragma unroll
    for (int k = 0; k < 10; k++) {
        acc[k] = fmaf(d, acc[k], bias[k]);
        m = fmaxf(m, acc[k]);
    }
    float s = 0.f;
    #pragma unroll
    for (int k = 0; k < 10; k++) s += expf(acc[k] - m);
    float ls = logf(s);
    #pragma unroll
    for (int k = 0; k < 10; k++) out[(long long)c * 10 + k] = acc[k] - m - ls;
}

// ---------------- MFMA matmul K=128, N=128 (W pre-packed) ----------------
// halfout=1: write to [2][M][32] u32 half-split layout (for the E0 half-gather).
__global__ __launch_bounds__(256) void mm128_kernel(
    const void* __restrict__ Av, const u32* __restrict__ Wp,
    u32* __restrict__ out, int M,
    const float* __restrict__ dis,
    const u32* __restrict__ gsrc, const int* __restrict__ gidx,
    const float* __restrict__ bias,
    const float* __restrict__ bnscale, const float* __restrict__ bnshift,
    int pool, int afp32,
    const int* __restrict__ pp, const int* __restrict__ childl, int apool,
    int halfout)
{
    __shared__ u32 WL[8192];   // [t=8][s=4][lane=64][i=4]
    int tid = threadIdx.x;
    {
        const uint4* ws4 = (const uint4*)Wp;
        uint4* wd4 = (uint4*)WL;
        #pragma unroll
        for (int it = 0; it < 8; it++) wd4[it * 256 + tid] = ws4[it * 256 + tid];
    }
    __syncthreads();

    int lane = tid & 63;
    int w = tid >> 6;
    int m = lane & 15, q = lane >> 4;
    int row = blockIdx.x * 64 + w * 16 + m;
    bool live = (row < M);

    uint4 xb[4];
    if (live) {
        if (apool) {
            float fa[32];
            #pragma unroll
            for (int i = 0; i < 32; i++) fa[i] = 0.f;
            const u32* Hb = (const u32*)Av;
            int e = pp[row], eE = pp[row + 1];
            for (; e < eE; e++) {
                long long cb = (long long)childl[e] * 64;
                #pragma unroll
                for (int s = 0; s < 4; s++) {
                    uint4 vv = *(const uint4*)(Hb + cb + s * 16 + q * 4);
                    fa[s * 8 + 0] += bl(vv.x); fa[s * 8 + 1] += bh(vv.x);
                    fa[s * 8 + 2] += bl(vv.y); fa[s * 8 + 3] += bh(vv.y);
                    fa[s * 8 + 4] += bl(vv.z); fa[s * 8 + 5] += bh(vv.z);
                    fa[s * 8 + 6] += bl(vv.w); fa[s * 8 + 7] += bh(vv.w);
                }
            }
            #pragma unroll
            for (int s = 0; s < 4; s++) {
                xb[s].x = pack2(fa[s * 8 + 0], fa[s * 8 + 1]);
                xb[s].y = pack2(fa[s * 8 + 2], fa[s * 8 + 3]);
                xb[s].z = pack2(fa[s * 8 + 4], fa[s * 8 + 5]);
                xb[s].w = pack2(fa[s * 8 + 6], fa[s * 8 + 7]);
            }
        } else if (afp32) {
            const float* Af = (const float*)Av;
            #pragma unroll
            for (int s = 0; s < 4; s++) {
                const float4* p = (const float4*)(Af + (long long)row * 128 + s * 32 + q * 8);
                float4 f0 = p[0], f1 = p[1];
                xb[s].x = pack2(f0.x, f0.y);
                xb[s].y = pack2(f0.z, f0.w);
                xb[s].z = pack2(f1.x, f1.y);
                xb[s].w = pack2(f1.z, f1.w);
            }
        } else {
            const u32* Ab = (const u32*)Av;
            #pragma unroll
            for (int s = 0; s < 4; s++)
                xb[s] = *(const uint4*)(Ab + (long long)row * 64 + s * 16 + q * 4);
        }
    } else {
        xb[0] = xb[1] = xb[2] = xb[3] = make_uint4(0u, 0u, 0u, 0u);
    }

    float d = 1.0f;
    if (dis && live) d = dis[row];
    long long gbase = (gsrc && live) ? (long long)gidx[row] * 64 : 0;

    #pragma unroll
    for (int t = 0; t < 8; t++) {
        f32x4 acc = {0.f, 0.f, 0.f, 0.f};
        #pragma unroll
        for (int s = 0; s < 4; s++) {
            uint4 wa = *(const uint4*)&WL[((t * 4 + s) * 64 + lane) * 4];
            acc = __builtin_amdgcn_mfma_f32_16x16x32_bf16(asbf(wa), asbf(xb[s]), acc, 0, 0, 0);
        }
        if (live) {
            float v0 = acc[0], v1 = acc[1], v2 = acc[2], v3 = acc[3];
            int cbase = t * 16 + q * 4;
            if (gsrc) {
                uint2 g = *(const uint2*)(gsrc + gbase + (cbase >> 1));
                v0 += bl(g.x); v1 += bh(g.x);
                v2 += bl(g.y); v3 += bh(g.y);
            }
            if (pool) {
                float4 bb = *(const float4*)(bias + cbase);
                float4 sc = *(const float4*)(bnscale + cbase);
                float4 sh = *(const float4*)(bnshift + cbase);
                v0 = fmaxf(fmaxf(v0 + bb.x, 0.f) * sc.x + sh.x, 0.f);
                v1 = fmaxf(fmaxf(v1 + bb.y, 0.f) * sc.y + sh.y, 0.f);
                v2 = fmaxf(fmaxf(v2 + bb.z, 0.f) * sc.z + sh.z, 0.f);
                v3 = fmaxf(fmaxf(v3 + bb.w, 0.f) * sc.w + sh.w, 0.f);
            }
            v0 *= d; v1 *= d; v2 *= d; v3 *= d;
            uint2 st;
            st.x = pack2(v0, v1);
            st.y = pack2(v2, v3);
            if (halfout)
                *(uint2*)(out + ((long long)(t >> 2) * M + row) * 32 + (t & 3) * 8 + q * 2) = st;
            else
                *(uint2*)(out + (long long)row * 64 + (cbase >> 1)) = st;
        }
    }
}

// ---------------- fused (pool-mm -> mm) + optional T0 side-GEMM blocks ----------------
// Blocks >= (M+63)/64 compute T0 = A @ W10 (fp32 out) -- identical FP order to old mm10p GEMM.
#define TLP 68
__global__ __launch_bounds__(256) void mm128x2_kernel(
    const u32* __restrict__ Av, const u32* __restrict__ Wa, const u32* __restrict__ Wb,
    u32* __restrict__ out, int M,
    const float* __restrict__ dis2,
    const float* __restrict__ bias1,
    const float* __restrict__ bnscale1, const float* __restrict__ bnshift1,
    const int* __restrict__ pp, const int* __restrict__ childl, int apool,
    const float* __restrict__ W10, float* __restrict__ T0out, int Mt0)
{
    __shared__ u32 WL[8192];
    __shared__ u32 TL[64 * TLP];
    int tid = threadIdx.x;
    int nmm = (M + 63) >> 6;
    if ((int)blockIdx.x >= nmm) {
        // ---- T0 side blocks: rows of Av (u32 bf16x2) @ W10[128][10] -> fp32 ----
        int rowt = ((int)blockIdx.x - nmm) * 256 + tid;
        if (rowt < Mt0) {
            const uint4* a = (const uint4*)(Av + (long long)rowt * 64);
            float acc[10] = {0, 0, 0, 0, 0, 0, 0, 0, 0, 0};
            #pragma unroll 4
            for (int i = 0; i < 16; i++) {
                uint4 av = a[i];
                int k = i * 8;
                float f[8] = { bl(av.x), bh(av.x), bl(av.y), bh(av.y),
                               bl(av.z), bh(av.z), bl(av.w), bh(av.w) };
                #pragma unroll
                for (int j = 0; j < 8; j++) {
                    #pragma unroll
                    for (int cc = 0; cc < 10; cc++)
                        acc[cc] += f[j] * W10[(k + j) * 10 + cc];
                }
            }
            #pragma unroll
            for (int cc = 0; cc < 10; cc++) T0out[(long long)rowt * 10 + cc] = acc[cc];
        }
        return;
    }
    {
        const uint4* ws4 = (const uint4*)Wa;
        uint4* wd4 = (uint4*)WL;
        #pragma unroll
        for (int it = 0; it < 8; it++) wd4[it * 256 + tid] = ws4[it * 256 + tid];
    }
    __syncthreads();

    int lane = tid & 63;
    int w = tid >> 6;
    int m = lane & 15, q = lane >> 4;
    int row = blockIdx.x * 64 + w * 16 + m;
    bool live = (row < M);

    // ---- stage 1 A fragments ----
    uint4 xb[4];
    if (live) {
        if (apool) {
            float fa[32];
            #pragma unroll
            for (int i = 0; i < 32; i++) fa[i] = 0.f;
            int e = pp[row], eE = pp[row + 1];
            for (; e < eE; e++) {
                long long cb = (long long)childl[e] * 64;
                #pragma unroll
                for (int s = 0; s < 4; s++) {
                    uint4 vv = *(const uint4*)(Av + cb + s * 16 + q * 4);
                    fa[s * 8 + 0] += bl(vv.x); fa[s * 8 + 1] += bh(vv.x);
                    fa[s * 8 + 2] += bl(vv.y); fa[s * 8 + 3] += bh(vv.y);
                    fa[s * 8 + 4] += bl(vv.z); fa[s * 8 + 5] += bh(vv.z);
                    fa[s * 8 + 6] += bl(vv.w); fa[s * 8 + 7] += bh(vv.w);
                }
            }
            #pragma unroll
            for (int s = 0; s < 4; s++) {
                xb[s].x = pack2(fa[s * 8 + 0], fa[s * 8 + 1]);
                xb[s].y = pack2(fa[s * 8 + 2], fa[s * 8 + 3]);
                xb[s].z = pack2(fa[s * 8 + 4], fa[s * 8 + 5]);
                xb[s].w = pack2(fa[s * 8 + 6], fa[s * 8 + 7]);
            }
        } else {
            #pragma unroll
            for (int s = 0; s < 4; s++)
                xb[s] = *(const uint4*)(Av + (long long)row * 64 + s * 16 + q * 4);
        }
    } else {
        xb[0] = xb[1] = xb[2] = xb[3] = make_uint4(0u, 0u, 0u, 0u);
    }

    u32* tl = TL + (w * 16 + m) * TLP;

    #pragma unroll
    for (int t = 0; t < 8; t++) {
        f32x4 acc = {0.f, 0.f, 0.f, 0.f};
        #pragma unroll
        for (int s = 0; s < 4; s++) {
            uint4 wa4 = *(const uint4*)&WL[((t * 4 + s) * 64 + lane) * 4];
            acc = __builtin_amdgcn_mfma_f32_16x16x32_bf16(asbf(wa4), asbf(xb[s]), acc, 0, 0, 0);
        }
        int cbase = t * 16 + q * 4;
        float4 bb = *(const float4*)(bias1 + cbase);
        float4 sc = *(const float4*)(bnscale1 + cbase);
        float4 sh = *(const float4*)(bnshift1 + cbase);
        float v0 = fmaxf(fmaxf(acc[0] + bb.x, 0.f) * sc.x + sh.x, 0.f);
        float v1 = fmaxf(fmaxf(acc[1] + bb.y, 0.f) * sc.y + sh.y, 0.f);
        float v2 = fmaxf(fmaxf(acc[2] + bb.z, 0.f) * sc.z + sh.z, 0.f);
        float v3 = fmaxf(fmaxf(acc[3] + bb.w, 0.f) * sc.w + sh.w, 0.f);
        uint2 st;
        st.x = pack2(v0, v1);
        st.y = pack2(v2, v3);
        *(uint2*)&tl[t * 8 + q * 2] = st;
    }
    __syncthreads();
    {
        const uint4* ws4 = (const uint4*)Wb;
        uint4* wd4 = (uint4*)WL;
        #pragma unroll
        for (int it = 0; it < 8; it++) wd4[it * 256 + tid] = ws4[it * 256 + tid];
    }
    __syncthreads();

    // ---- stage 2 ----
    #pragma unroll
    for (int s = 0; s < 4; s++)
        xb[s] = *(const uint4*)&tl[s * 16 + q * 4];
    float d = 1.0f;
    if (dis2 && live) d = dis2[row];

    #pragma unroll
    for (int t = 0; t < 8; t++) {
        f32x4 acc = {0.f, 0.f, 0.f, 0.f};
        #pragma unroll
        for (int s = 0; s < 4; s++) {
            uint4 wa4 = *(const uint4*)&WL[((t * 4 + s) * 64 + lane) * 4];
            acc = __builtin_amdgcn_mfma_f32_16x16x32_bf16(asbf(wa4), asbf(xb[s]), acc, 0, 0, 0);
        }
        if (live) {
            int cbase = t * 16 + q * 4;
            float v0 = acc[0] * d, v1 = acc[1] * d, v2 = acc[2] * d, v3 = acc[3] * d;
            uint2 st;
            st.x = pack2(v0, v1);
            st.y = pack2(v2, v3);
            *(uint2*)(out + (long long)row * 64 + (cbase >> 1)) = st;
        }
    }
}

// ---------------- fused up1: (pool-mm 128x128 w/ bias+bn+relu) -> mm K=128,N=10 ----------------
__global__ __launch_bounds__(256) void mm128_mm10_kernel(
    const u32* __restrict__ Av, const u32* __restrict__ Wp,
    const float* __restrict__ W10,
    float* __restrict__ out10, int M,
    const float* __restrict__ bias1,
    const float* __restrict__ bnscale1, const float* __restrict__ bnshift1)
{
    __shared__ u32 WL[8192];
    __shared__ u32 TL[64 * TLP];
    __shared__ float Ws[128 * 10];
    int tid = threadIdx.x;
    {
        const uint4* ws4 = (const uint4*)Wp;
        uint4* wd4 = (uint4*)WL;
        #pragma unroll
        for (int it = 0; it < 8; it++) wd4[it * 256 + tid] = ws4[it * 256 + tid];
    }
    for (int i = tid; i < 1280; i += 256) Ws[i] = W10[i];
    __syncthreads();

    int lane = tid & 63;
    int w = tid >> 6;
    int m = lane & 15, q = lane >> 4;
    int row = blockIdx.x * 64 + w * 16 + m;
    bool live = (row < M);

    uint4 xb[4];
    if (live) {
        #pragma unroll
        for (int s = 0; s < 4; s++)
            xb[s] = *(const uint4*)(Av + (long long)row * 64 + s * 16 + q * 4);
    } else {
        xb[0] = xb[1] = xb[2] = xb[3] = make_uint4(0u, 0u, 0u, 0u);
    }

    u32* tl = TL + (w * 16 + m) * TLP;

    #pragma unroll
    for (int t = 0; t < 8; t++) {
        f32x4 acc = {0.f, 0.f, 0.f, 0.f};
        #pragma unroll
        for (int s = 0; s < 4; s++) {
            uint4 wa4 = *(const uint4*)&WL[((t * 4 + s) * 64 + lane) * 4];
            acc = __builtin_amdgcn_mfma_f32_16x16x32_bf16(asbf(wa4), asbf(xb[s]), acc, 0, 0, 0);
        }
        int cbase = t * 16 + q * 4;
        float4 bb = *(const float4*)(bias1 + cbase);
        float4 sc = *(const float4*)(bnscale1 + cbase);
        float4 sh = *(const float4*)(bnshift1 + cbase);
        float v0 = fmaxf(fmaxf(acc[0] + bb.x, 0.f) * sc.x + sh.x, 0.f);
        float v1 = fmaxf(fmaxf(acc[1] + bb.y, 0.f) * sc.y + sh.y, 0.f);
        float v2 = fmaxf(fmaxf(acc[2] + bb.z, 0.f) * sc.z + sh.z, 0.f);
        float v3 = fmaxf(fmaxf(acc[3] + bb.w, 0.f) * sc.w + sh.w, 0.f);
        uint2 st;
        st.x = pack2(v0, v1);
        st.y = pack2(v2, v3);
        *(uint2*)&tl[t * 8 + q * 2] = st;
    }
    __syncthreads();

    // stage 2: 64 rows x 10 cols, dot over 128 (ascending k)
    int base = blockIdx.x * 64;
    for (int slot = tid; slot < 640; slot += 256) {
        int r = slot / 10, cc = slot % 10;
        if (base + r < M) {
            const u32* tr = &TL[r * TLP];
            float acc = 0.f;
            #pragma unroll
            for (int k2 = 0; k2 < 64; k2++) {
                u32 p = tr[k2];
                acc += bl(p) * Ws[(2 * k2) * 10 + cc];
                acc += bh(p) * Ws[(2 * k2 + 1) * 10 + cc];
            }
            out10[(long long)(base + r) * 10 + cc] = acc;
        }
    }
}

// ---------------- gcn4 epilogue: T0 + W1b[parent] add, dis scale, bf16 pack ----------------
__global__ __launch_bounds__(256) void mm10p2_kernel(
    const float* __restrict__ T0, const float* __restrict__ gsrc,
    const int* __restrict__ gidx, const float* __restrict__ dis,
    u32* __restrict__ outp, int M)
{
    int row = blockIdx.x * 256 + threadIdx.x;
    if (row >= M) return;
    float d = dis[row];
    const float* t = T0 + (long long)row * 10;
    const float* g = gsrc + (long long)gidx[row] * 10;
    long long base = (long long)row * 8;
    #pragma unroll
    for (int j = 0; j < 5; j++) {
        float v0 = (t[2 * j] + g[2 * j]) * d;
        float v1 = (t[2 * j + 1] + g[2 * j + 1]) * d;
        outp[base + j] = pack2(v0, v1);
    }
}

// ---------------- launcher ----------------

extern "C" void kernel_launch(void* const* d_in, const int* in_sizes, int n_in,
                              void* d_out, int out_size, void* d_ws, size_t ws_size,
                              hipStream_t stream) {
    const float* x       = (const float*)d_in[0];
    const int*   ei0     = (const int*)d_in[1];
    const int*   ei1     = (const int*)d_in[2];
    const int*   ei2     = (const int*)d_in[3];
    const int*   parent1 = (const int*)d_in[4];
    const int*   parent2 = (const int*)d_in[5];
    const float* W0 = (const float*)d_in[6];
    const float* b0 = (const float*)d_in[7];
    const float* W1 = (const float*)d_in[8];
    const float* b1 = (const float*)d_in[9];
    const float* W2 = (const float*)d_in[10];
    const float* b2 = (const float*)d_in[11];
    const float* W3 = (const float*)d_in[12];
    const float* b3 = (const float*)d_in[13];
    const float* W4 = (const float*)d_in[14];
    const float* b4 = (const float*)d_in[15];
    const float* pW = (const float*)d_in[16];
    const float* pb = (const float*)d_in[17];
    const float* pg = (const float*)d_in[18];
    const float* pbeta = (const float*)d_in[19];
    const float* pmean = (const float*)d_in[20];
    const float* pvar  = (const float*)d_in[21];
    float* out = (float*)d_out;

    char* ws = (char*)d_ws;
    size_t off = 0;
    auto alloc = [&](size_t nbytes) -> char* {
        char* p = ws + off;
        off += ((nbytes + 255) / 256) * 256;
        return p;
    };
    float* dis0 = (float*)alloc(N0 * 4);
    float* dis1 = (float*)alloc(N1 * 4);
    float* dis2 = (float*)alloc(N2 * 4);
    float* bnscale = (float*)alloc(4 * HDIM * 4);
    float* bnshift = (float*)alloc(4 * HDIM * 4);
    float* W1b = (float*)alloc((size_t)N1 * 10 * 4);
    float* T0  = (float*)alloc((size_t)N0 * 10 * 4);
    u32* Y   = (u32*)alloc((size_t)N0 * 64 * 4);   // also used as [2][N0][32] halves for gcn0
    u32* H0  = (u32*)alloc((size_t)N0 * 64 * 4);
    u32* H1  = (u32*)alloc((size_t)N1 * 64 * 4);
    u32* HU1 = (u32*)alloc((size_t)N1 * 64 * 4);
    u32* H2  = (u32*)alloc((size_t)N2 * 64 * 4);
    u32* V2  = (u32*)alloc((size_t)N2 * 64 * 4);
    u32* Y4p = (u32*)alloc((size_t)N0 * 8 * 4);
    u32* Wpk = (u32*)alloc((size_t)NWMAT * 8192 * 4);
    int* rpAll = (int*)alloc((size_t)(OFFT + 1) * 4);
    int* srcU  = (int*)alloc((size_t)S4 * 4);
    int* blockHist = (int*)alloc((size_t)BH_N * 4);
    int* OfsAbs    = (int*)alloc((size_t)(BH_N + 1) * 4);
    u32* binPair   = (u32*)alloc((size_t)S4 * 4);
    int* bsum   = (int*)alloc(NBLK2 * 4);
    int* totalb = (int*)alloc(4);

    const int B = 256;
    auto G = [](long long t) { return (unsigned)((t + 255) / 256); };
    auto G64 = [](long long m) { return (unsigned)((m + 63) / 64); };

    // ---- CSR build (+ W prepack hidden in binhist grid) ----
    binhist_kernel<<<NBA + NWMAT, B, 0, stream>>>(
        ei0 + E0C, ei1 + E1C, ei2 + E2C, parent1, parent2, blockHist,
        W0, W1, W2, W3, pW, Wpk);
    scan_k1<<<NBLK2, B, 0, stream>>>(blockHist, bsum, BH_N);
    scan_k2<<<1, B, 0, stream>>>(bsum, totalb, NBLK2, pg, pbeta, pmean, pvar, bnscale, bnshift);
    scan_k3<<<NBLK2, B, 0, stream>>>(blockHist, bsum, totalb, OfsAbs, BH_N);
    binfill_kernel<<<NBA, B, 0, stream>>>(
        ei0, ei0 + E0C, ei1, ei1 + E1C, ei2, ei2 + E2C, parent1, parent2, OfsAbs, binPair);
    bucket_build_kernel<<<NBUCK, 1024, 0, stream>>>(
        binPair, OfsAbs, rpAll, srcU, dis0, dis1, dis2);

    // ---- gcn0 (Y written as two feature-halves [2][N0][32]) ----
    mm128_kernel<<<G64(N0), B, 0, stream>>>(
        x, Wpk + 0 * 8192, Y, N0, dis0, nullptr, nullptr, nullptr, nullptr, nullptr, 0, 1,
        nullptr, nullptr, 0, 1);
    // two temporally-separated half-passes: working set 12.8 MB each
    gather128h_kernel<<<G((long long)N0 * 64), B, 0, stream>>>(
        rpAll + OFF0, srcU, Y, dis0, b0, H0, N0);
    gather128h_kernel<<<G((long long)N0 * 64), B, 0, stream>>>(
        rpAll + OFF0, srcU, Y + (long long)N0 * 32, dis0, b0 + 64, H0 + 32, N0);

    // ---- pool1 + gcn1 (fused) + T0 = H0 @ W4lo side blocks ----
    mm128x2_kernel<<<G64(N1) + G(N0), B, 0, stream>>>(
        H0, Wpk + 5 * 8192, Wpk + 1 * 8192, Y, N1, dis1,
        pb, bnscale, bnshift, rpAll + OFF3, srcU, 1,
        W4 + 128 * 10, T0, N0);
    gather128_kernel<<<G((long long)N1 * 64), B, 0, stream>>>(rpAll + OFF1, srcU, Y, dis1, b1, H1, N1);

    // ---- pool2 + gcn2 (fused) ----
    mm128x2_kernel<<<G64(N2), B, 0, stream>>>(
        H1, Wpk + 6 * 8192, Wpk + 2 * 8192, Y, N2, dis2,
        pb + 128, bnscale + 128, bnshift + 128, rpAll + OFF4, srcU, 1,
        nullptr, nullptr, 0);
    gather128_kernel<<<G((long long)N2 * 64), B, 0, stream>>>(rpAll + OFF2, srcU, Y, dis2, b2, H2, N2);

    // ---- up level 2 (fused pool + mm) ----
    mm128x2_kernel<<<G64(N2), B, 0, stream>>>(
        H2, Wpk + 7 * 8192, Wpk + 3 * 8192, V2, N2, nullptr,
        pb + 256, bnscale + 256, bnshift + 256, nullptr, nullptr, 0,
        nullptr, nullptr, 0);

    // ---- gcn3 ----
    mm128_kernel<<<G64(N1), B, 0, stream>>>(
        H1, Wpk + 4 * 8192, Y, N1, dis1, V2, parent2, nullptr, nullptr, nullptr, 0, 0,
        nullptr, nullptr, 0, 0);
    gather128_kernel<<<G((long long)N1 * 64), B, 0, stream>>>(rpAll + OFF1, srcU, Y, dis1, b3, HU1, N1);

    // ---- up level 1 (fused pool-mm + N=10 matmul) ----
    mm128_mm10_kernel<<<G64(N1), B, 0, stream>>>(
        HU1, Wpk + 8 * 8192, W4, W1b, N1, pb + 384, bnscale + 384, bnshift + 384);

    // ---- gcn4 ----
    mm10p2_kernel<<<G(N0), B, 0, stream>>>(T0, W1b, parent1, dis0, Y4p, N0);
    gather10_lsm_kernel<<<G(N0), B, 0, stream>>>(rpAll + OFF0, srcU, Y4p, dis0, b4, out, N0);
}

// Round 7
// 375.678 us; speedup vs baseline: 1.1244x; 1.1244x over previous
//
#include <hip/hip_runtime.h>
#include <math.h>

#define N0 100000
#define N1 20000
#define N2 4000
#define HDIM 128
#define E0C 1600000
#define E1C 320000
#define E2C 64000
#define EPSBN 1e-5f

typedef unsigned int u32;
typedef float f32x4 __attribute__((ext_vector_type(4)));
typedef short bf16x8 __attribute__((ext_vector_type(8)));

union FragU { uint4 u; bf16x8 h; };
__device__ __forceinline__ bf16x8 asbf(uint4 v) { FragU x; x.u = v; return x.h; }

__device__ __forceinline__ float bl(u32 p) { return __uint_as_float(p << 16); }
__device__ __forceinline__ float bh(u32 p) { return __uint_as_float(p & 0xFFFF0000u); }
__device__ __forceinline__ u32 pack2(float a, float b) {
    u32 ua = __float_as_uint(a), ub = __float_as_uint(b);
    ua = (ua + 0x7FFFu + ((ua >> 16) & 1u)) >> 16;
    ub = (ub + 0x7FFFu + ((ub >> 16) & 1u)) >> 16;
    return ua | (ub << 16);
}

// concatenated destination space
#define OFF0 0
#define OFF1 (N0)
#define OFF2 (N0 + N1)
#define OFF3 (N0 + N1 + N2)
#define OFF4 (N0 + N1 + N2 + N1)
#define OFFT (N0 + N1 + N2 + N1 + N2)        // 148000

// concatenated work items
#define S0 (E0C)
#define S1 (E0C + E1C)
#define S2 (E0C + E1C + E2C)
#define S3 (E0C + E1C + E2C + N0)
#define S4 (E0C + E1C + E2C + N0 + N1)       // 2,104,000

// counting-sort geometry
#define NBUCK ((OFFT + 1023) / 1024)         // 145 coarse buckets
#define ITEMS_PER_BLK 2048
#define NBA ((S4 + ITEMS_PER_BLK - 1) / ITEMS_PER_BLK)   // 1028 blocks
#define BH_N (NBUCK * NBA)
#define NBLK2 ((BH_N + 1023) / 1024)

#define NWMAT 9   // W0,W1,W2,W3lo,W3hi,pW0..3 packed matrices

// ---------------- CSR build (LDS counting sort, zero global atomics) ----------------
// binPair entry: (concat&1023)<<17 | payload   (payload < 2^17, bucket implied by position)

__device__ __forceinline__ void item_full(int g,
    const int* __restrict__ ei0r, const int* __restrict__ ei0c,
    const int* __restrict__ ei1r, const int* __restrict__ ei1c,
    const int* __restrict__ ei2r, const int* __restrict__ ei2c,
    const int* __restrict__ p1, const int* __restrict__ p2,
    int& concat, int& payload)
{
    if (g < S0)      { concat = ei0c[g];             payload = ei0r[g]; }
    else if (g < S1) { int i = g - S0; concat = OFF1 + ei1c[i]; payload = ei1r[i]; }
    else if (g < S2) { int i = g - S1; concat = OFF2 + ei2c[i]; payload = ei2r[i]; }
    else if (g < S3) { int i = g - S2; concat = OFF3 + p1[i];   payload = i; }
    else             { int i = g - S3; concat = OFF4 + p2[i];   payload = i; }
}

__device__ __forceinline__ int item_concat(int g,
    const int* __restrict__ ei0c, const int* __restrict__ ei1c, const int* __restrict__ ei2c,
    const int* __restrict__ p1, const int* __restrict__ p2)
{
    if (g < S0)      return ei0c[g];
    else if (g < S1) return OFF1 + ei1c[g - S0];
    else if (g < S2) return OFF2 + ei2c[g - S1];
    else if (g < S3) return OFF3 + p1[g - S2];
    else             return OFF4 + p2[g - S3];
}

// binhist + W prepack merged: blocks [0,NBA) histogram, [NBA,NBA+9) pack weights.
__global__ __launch_bounds__(256) void binhist_kernel(
    const int* __restrict__ ei0c, const int* __restrict__ ei1c, const int* __restrict__ ei2c,
    const int* __restrict__ p1, const int* __restrict__ p2,
    int* __restrict__ blockHist,
    const float* __restrict__ W0p, const float* __restrict__ W1p,
    const float* __restrict__ W2p, const float* __restrict__ W3p,
    const float* __restrict__ pWp, u32* __restrict__ Wpk)
{
    __shared__ int hist[NBUCK];
    int tid = threadIdx.x, blk = blockIdx.x;
    if (blk >= NBA) {
        int b = blk - NBA;
        const float* src;
        if (b == 0) src = W0p;
        else if (b == 1) src = W1p;
        else if (b == 2) src = W2p;
        else if (b == 3) src = W3p;
        else if (b == 4) src = W3p + 128 * 128;
        else src = pWp + (b - 5) * 128 * 128;
        u32* dst = Wpk + b * 8192;
        #pragma unroll
        for (int it = 0; it < 32; it++) {
            int flat = it * 256 + tid;
            int i = flat & 3;
            int ln = (flat >> 2) & 63;
            int s = (flat >> 8) & 3;
            int t = flat >> 10;
            int mm = ln & 15, qq = ln >> 4;
            int k0 = s * 32 + qq * 8 + 2 * i;
            int col = t * 16 + mm;
            dst[flat] = pack2(src[k0 * 128 + col], src[(k0 + 1) * 128 + col]);
        }
        return;
    }
    for (int i = tid; i < NBUCK; i += 256) hist[i] = 0;
    __syncthreads();
    int base = blk * ITEMS_PER_BLK;
    #pragma unroll
    for (int k = 0; k < ITEMS_PER_BLK / 256; k++) {
        int g = base + k * 256 + tid;
        if (g < S4) {
            int c = item_concat(g, ei0c, ei1c, ei2c, p1, p2);
            atomicAdd(&hist[c >> 10], 1);
        }
    }
    __syncthreads();
    for (int b = tid; b < NBUCK; b += 256) blockHist[b * NBA + blk] = hist[b];
}

__global__ __launch_bounds__(256) void scan_k1(const int* __restrict__ c, int* __restrict__ bsum, int n) {
    int t = threadIdx.x;
    int base = blockIdx.x * 1024 + t * 4;
    int s = 0;
    #pragma unroll
    for (int j = 0; j < 4; j++) {
        int idx = base + j;
        if (idx < n) s += c[idx];
    }
    #pragma unroll
    for (int o = 32; o > 0; o >>= 1) s += __shfl_down(s, o, 64);
    __shared__ int ws[4];
    if ((t & 63) == 0) ws[t >> 6] = s;
    __syncthreads();
    if (t == 0) bsum[blockIdx.x] = ws[0] + ws[1] + ws[2] + ws[3];
}

// scan_k2 + folded bn_pre (512 scale/shift elems, 2 per thread)
__global__ __launch_bounds__(256) void scan_k2(int* __restrict__ bsum, int* __restrict__ totalOut, int nb,
    const float* __restrict__ g, const float* __restrict__ beta,
    const float* __restrict__ mean, const float* __restrict__ var,
    float* __restrict__ scale, float* __restrict__ shift)
{
    int t = threadIdx.x;
    #pragma unroll
    for (int j = 0; j < 2; j++) {
        int i = j * 256 + t;
        float s = g[i] * rsqrtf(var[i] + EPSBN);
        scale[i] = s;
        shift[i] = beta[i] - mean[i] * s;
    }
    int v = (t < nb) ? bsum[t] : 0;
    __shared__ int ts[256];
    ts[t] = v;
    __syncthreads();
    for (int o = 1; o < 256; o <<= 1) {
        int u = (t >= o) ? ts[t - o] : 0;
        __syncthreads();
        ts[t] += u;
        __syncthreads();
    }
    if (t < nb) bsum[t] = ts[t] - v;
    if (t == nb - 1) *totalOut = ts[t];
}

__global__ __launch_bounds__(256) void scan_k3(const int* __restrict__ c, const int* __restrict__ bsum,
                                               const int* __restrict__ total,
                                               int* __restrict__ S, int n) {
    int t = threadIdx.x;
    int base = blockIdx.x * 1024 + t * 4;
    int v[4];
    #pragma unroll
    for (int j = 0; j < 4; j++) v[j] = (base + j < n) ? c[base + j] : 0;
    int tsum = v[0] + v[1] + v[2] + v[3];
    __shared__ int ts[256];
    ts[t] = tsum;
    __syncthreads();
    for (int o = 1; o < 256; o <<= 1) {
        int u = (t >= o) ? ts[t - o] : 0;
        __syncthreads();
        ts[t] += u;
        __syncthreads();
    }
    int run = bsum[blockIdx.x] + ts[t] - tsum;
    #pragma unroll
    for (int j = 0; j < 4; j++) {
        if (base + j < n) { S[base + j] = run; run += v[j]; }
    }
    if (blockIdx.x == 0 && t == 0) S[n] = *total;
}

__global__ __launch_bounds__(256) void binfill_kernel(
    const int* __restrict__ ei0r, const int* __restrict__ ei0c,
    const int* __restrict__ ei1r, const int* __restrict__ ei1c,
    const int* __restrict__ ei2r, const int* __restrict__ ei2c,
    const int* __restrict__ p1, const int* __restrict__ p2,
    const int* __restrict__ OfsAbs, u32* __restrict__ binPair)
{
    __shared__ int cur[NBUCK];
    int tid = threadIdx.x, blk = blockIdx.x;
    for (int i = tid; i < NBUCK; i += 256) cur[i] = OfsAbs[i * NBA + blk];
    __syncthreads();
    int base = blk * ITEMS_PER_BLK;
    #pragma unroll
    for (int k = 0; k < ITEMS_PER_BLK / 256; k++) {
        int g = base + k * 256 + tid;
        if (g < S4) {
            int c, p;
            item_full(g, ei0r, ei0c, ei1r, ei1c, ei2r, ei2c, p1, p2, c, p);
            int pos = atomicAdd(&cur[c >> 10], 1);
            binPair[pos] = ((u32)(c & 1023) << 17) | (u32)p;
        }
    }
}

__global__ __launch_bounds__(1024) void bucket_build_kernel(
    const u32* __restrict__ binPair, const int* __restrict__ OfsAbs,
    int* __restrict__ rpAll, int* __restrict__ srcU,
    float* __restrict__ dis0, float* __restrict__ dis1, float* __restrict__ dis2)
{
    __shared__ int cnt_l[1024];
    __shared__ int rp_l[1024];
    __shared__ int wsum[16];
    int b = blockIdx.x, tid = threadIdx.x;
    int start = OfsAbs[b * NBA];
    int end = (b + 1 < NBUCK) ? OfsAbs[(b + 1) * NBA] : S4;
    int d0 = b << 10;
    int nd = OFFT - d0; if (nd > 1024) nd = 1024;

    cnt_l[tid] = 0;
    __syncthreads();
    for (int i = start + tid; i < end; i += 1024) {
        u32 e = binPair[i];
        atomicAdd(&cnt_l[e >> 17], 1);
    }
    __syncthreads();
    int v = cnt_l[tid];
    int lane = tid & 63, wv = tid >> 6;
    int s = v;
    #pragma unroll
    for (int o = 1; o < 64; o <<= 1) {
        int u = __shfl_up(s, o, 64);
        if (lane >= o) s += u;
    }
    if (lane == 63) wsum[wv] = s;
    __syncthreads();
    if (wv == 0) {
        int t2 = (lane < 16) ? wsum[lane] : 0;
        #pragma unroll
        for (int o = 1; o < 16; o <<= 1) {
            int u = __shfl_up(t2, o, 64);
            if (lane >= o) t2 += u;
        }
        if (lane < 16) wsum[lane] = t2;
    }
    __syncthreads();
    int incl = s + (wv ? wsum[wv - 1] : 0);
    rp_l[tid] = incl - v;   // exclusive scan
    __syncthreads();
    if (tid < nd) {
        int g = d0 + tid;
        rpAll[g] = start + rp_l[tid];
        float dv = rsqrtf((float)(v + 1));
        if (g < OFF1) dis0[g] = dv;
        else if (g < OFF2) dis1[g - OFF1] = dv;
        else if (g < OFF3) dis2[g - OFF2] = dv;
    }
    if (b == NBUCK - 1 && tid == 0) rpAll[OFFT] = S4;
    __syncthreads();
    for (int i = start + tid; i < end; i += 1024) {
        u32 e = binPair[i];
        int pos = start + atomicAdd(&rp_l[e >> 17], 1);
        srcU[pos] = (int)(e & 0x1FFFFu);
    }
}

// ---------------- gather kernels (bf16 features, fp32 accumulate) ----------------

#define G128_LOAD(sym, off) u32 sym = y[(long long)srcl[e + off] * 64 + lane]

__global__ __launch_bounds__(256) void gather128_kernel(
    const int* __restrict__ rp, const int* __restrict__ srcl,
    const u32* __restrict__ y, const float* __restrict__ dis,
    const float* __restrict__ bias, u32* __restrict__ h, int n)
{
    int wid = (int)((blockIdx.x * 256 + threadIdx.x) >> 6);
    int lane = threadIdx.x & 63;
    if (wid >= n) return;
    u32 self = y[(long long)wid * 64 + lane];
    float ax = bl(self), ay = bh(self);
    int e = rp[wid], e1 = rp[wid + 1];
    for (; e + 7 < e1; e += 8) {
        G128_LOAD(p0, 0); G128_LOAD(p1, 1); G128_LOAD(p2, 2); G128_LOAD(p3, 3);
        G128_LOAD(p4, 4); G128_LOAD(p5, 5); G128_LOAD(p6, 6); G128_LOAD(p7, 7);
        ax += ((bl(p0) + bl(p1)) + (bl(p2) + bl(p3))) + ((bl(p4) + bl(p5)) + (bl(p6) + bl(p7)));
        ay += ((bh(p0) + bh(p1)) + (bh(p2) + bh(p3))) + ((bh(p4) + bh(p5)) + (bh(p6) + bh(p7)));
    }
    if (e + 3 < e1) {
        G128_LOAD(p0, 0); G128_LOAD(p1, 1); G128_LOAD(p2, 2); G128_LOAD(p3, 3);
        ax += (bl(p0) + bl(p1)) + (bl(p2) + bl(p3));
        ay += (bh(p0) + bh(p1)) + (bh(p2) + bh(p3));
        e += 4;
    }
    if (e + 1 < e1) {
        G128_LOAD(p0, 0); G128_LOAD(p1, 1);
        ax += bl(p0) + bl(p1);
        ay += bh(p0) + bh(p1);
        e += 2;
    }
    if (e < e1) {
        G128_LOAD(p0, 0);
        ax += bl(p0); ay += bh(p0);
    }
    float d = dis[wid];
    float2 b = ((const float2*)bias)[lane];
    float r0 = fmaxf(fmaf(d, ax, b.x), 0.f);
    float r1 = fmaxf(fmaf(d, ay, b.y), 0.f);
    h[(long long)wid * 64 + lane] = pack2(r0, r1);
}

__global__ __launch_bounds__(256) void gather10_lsm_kernel(
    const int* __restrict__ rp, const int* __restrict__ srcl,
    const u32* __restrict__ y4, const float* __restrict__ dis,
    const float* __restrict__ bias, float* __restrict__ out, int n)
{
    int c = blockIdx.x * blockDim.x + threadIdx.x;
    if (c >= n) return;
    float acc[10];
    {
        long long base = (long long)c * 8;
        uint4 q = *(const uint4*)(y4 + base);
        u32 q4 = y4[base + 4];
        acc[0] = bl(q.x); acc[1] = bh(q.x);
        acc[2] = bl(q.y); acc[3] = bh(q.y);
        acc[4] = bl(q.z); acc[5] = bh(q.z);
        acc[6] = bl(q.w); acc[7] = bh(q.w);
        acc[8] = bl(q4);  acc[9] = bh(q4);
    }
    int e = rp[c], e1 = rp[c + 1];
    for (; e + 3 < e1; e += 4) {
        long long bA = (long long)srcl[e] * 8;
        long long bB = (long long)srcl[e + 1] * 8;
        long long bC = (long long)srcl[e + 2] * 8;
        long long bD = (long long)srcl[e + 3] * 8;
        uint4 qa = *(const uint4*)(y4 + bA); u32 qa4 = y4[bA + 4];
        uint4 qb = *(const uint4*)(y4 + bB); u32 qb4 = y4[bB + 4];
        uint4 qc = *(const uint4*)(y4 + bC); u32 qc4 = y4[bC + 4];
        uint4 qd = *(const uint4*)(y4 + bD); u32 qd4 = y4[bD + 4];
        acc[0] += (bl(qa.x) + bl(qb.x)) + (bl(qc.x) + bl(qd.x));
        acc[1] += (bh(qa.x) + bh(qb.x)) + (bh(qc.x) + bh(qd.x));
        acc[2] += (bl(qa.y) + bl(qb.y)) + (bl(qc.y) + bl(qd.y));
        acc[3] += (bh(qa.y) + bh(qb.y)) + (bh(qc.y) + bh(qd.y));
        acc[4] += (bl(qa.z) + bl(qb.z)) + (bl(qc.z) + bl(qd.z));
        acc[5] += (bh(qa.z) + bh(qb.z)) + (bh(qc.z) + bh(qd.z));
        acc[6] += (bl(qa.w) + bl(qb.w)) + (bl(qc.w) + bl(qd.w));
        acc[7] += (bh(qa.w) + bh(qb.w)) + (bh(qc.w) + bh(qd.w));
        acc[8] += (bl(qa4) + bl(qb4)) + (bl(qc4) + bl(qd4));
        acc[9] += (bh(qa4) + bh(qb4)) + (bh(qc4) + bh(qd4));
    }
    for (; e < e1; e++) {
        long long bA = (long long)srcl[e] * 8;
        uint4 qa = *(const uint4*)(y4 + bA);
        u32 qa4 = y4[bA + 4];
        acc[0] += bl(qa.x); acc[1] += bh(qa.x);
        acc[2] += bl(qa.y); acc[3] += bh(qa.y);
        acc[4] += bl(qa.z); acc[5] += bh(qa.z);
        acc[6] += bl(qa.w); acc[7] += bh(qa.w);
        acc[8] += bl(qa4);  acc[9] += bh(qa4);
    }
    float d = dis[c];
    float m = -1e30f;
    #pragma unroll
    for (int k = 0; k < 10; k++) {
        acc[k] = fmaf(d, acc[k], bias[k]);
        m = fmaxf(m, acc[k]);
    }
    float s = 0.f;
    #pragma unroll
    for (int k = 0; k < 10; k++) s += expf(acc[k] - m);
    float ls = logf(s);
    #pragma unroll
    for (int k = 0; k < 10; k++) out[(long long)c * 10 + k] = acc[k] - m - ls;
}

// ---------------- MFMA matmul K=128, N=128 (W pre-packed) ----------------
__global__ __launch_bounds__(256) void mm128_kernel(
    const void* __restrict__ Av, const u32* __restrict__ Wp,
    u32* __restrict__ out, int M,
    const float* __restrict__ dis,
    const u32* __restrict__ gsrc, const int* __restrict__ gidx,
    const float* __restrict__ bias,
    const float* __restrict__ bnscale, const float* __restrict__ bnshift,
    int pool, int afp32,
    const int* __restrict__ pp, const int* __restrict__ childl, int apool)
{
    __shared__ u32 WL[8192];   // [t=8][s=4][lane=64][i=4]
    int tid = threadIdx.x;
    {
        const uint4* ws4 = (const uint4*)Wp;
        uint4* wd4 = (uint4*)WL;
        #pragma unroll
        for (int it = 0; it < 8; it++) wd4[it * 256 + tid] = ws4[it * 256 + tid];
    }
    __syncthreads();

    int lane = tid & 63;
    int w = tid >> 6;
    int m = lane & 15, q = lane >> 4;
    int row = blockIdx.x * 64 + w * 16 + m;
    bool live = (row < M);

    uint4 xb[4];
    if (live) {
        if (apool) {
            float fa[32];
            #pragma unroll
            for (int i = 0; i < 32; i++) fa[i] = 0.f;
            const u32* Hb = (const u32*)Av;
            int e = pp[row], eE = pp[row + 1];
            for (; e < eE; e++) {
                long long cb = (long long)childl[e] * 64;
                #pragma unroll
                for (int s = 0; s < 4; s++) {
                    uint4 vv = *(const uint4*)(Hb + cb + s * 16 + q * 4);
                    fa[s * 8 + 0] += bl(vv.x); fa[s * 8 + 1] += bh(vv.x);
                    fa[s * 8 + 2] += bl(vv.y); fa[s * 8 + 3] += bh(vv.y);
                    fa[s * 8 + 4] += bl(vv.z); fa[s * 8 + 5] += bh(vv.z);
                    fa[s * 8 + 6] += bl(vv.w); fa[s * 8 + 7] += bh(vv.w);
                }
            }
            #pragma unroll
            for (int s = 0; s < 4; s++) {
                xb[s].x = pack2(fa[s * 8 + 0], fa[s * 8 + 1]);
                xb[s].y = pack2(fa[s * 8 + 2], fa[s * 8 + 3]);
                xb[s].z = pack2(fa[s * 8 + 4], fa[s * 8 + 5]);
                xb[s].w = pack2(fa[s * 8 + 6], fa[s * 8 + 7]);
            }
        } else if (afp32) {
            const float* Af = (const float*)Av;
            #pragma unroll
            for (int s = 0; s < 4; s++) {
                const float4* p = (const float4*)(Af + (long long)row * 128 + s * 32 + q * 8);
                float4 f0 = p[0], f1 = p[1];
                xb[s].x = pack2(f0.x, f0.y);
                xb[s].y = pack2(f0.z, f0.w);
                xb[s].z = pack2(f1.x, f1.y);
                xb[s].w = pack2(f1.z, f1.w);
            }
        } else {
            const u32* Ab = (const u32*)Av;
            #pragma unroll
            for (int s = 0; s < 4; s++)
                xb[s] = *(const uint4*)(Ab + (long long)row * 64 + s * 16 + q * 4);
        }
    } else {
        xb[0] = xb[1] = xb[2] = xb[3] = make_uint4(0u, 0u, 0u, 0u);
    }

    float d = 1.0f;
    if (dis && live) d = dis[row];
    long long gbase = (gsrc && live) ? (long long)gidx[row] * 64 : 0;

    #pragma unroll
    for (int t = 0; t < 8; t++) {
        f32x4 acc = {0.f, 0.f, 0.f, 0.f};
        #pragma unroll
        for (int s = 0; s < 4; s++) {
            uint4 wa = *(const uint4*)&WL[((t * 4 + s) * 64 + lane) * 4];
            acc = __builtin_amdgcn_mfma_f32_16x16x32_bf16(asbf(wa), asbf(xb[s]), acc, 0, 0, 0);
        }
        if (live) {
            float v0 = acc[0], v1 = acc[1], v2 = acc[2], v3 = acc[3];
            int cbase = t * 16 + q * 4;
            if (gsrc) {
                uint2 g = *(const uint2*)(gsrc + gbase + (cbase >> 1));
                v0 += bl(g.x); v1 += bh(g.x);
                v2 += bl(g.y); v3 += bh(g.y);
            }
            if (pool) {
                float4 bb = *(const float4*)(bias + cbase);
                float4 sc = *(const float4*)(bnscale + cbase);
                float4 sh = *(const float4*)(bnshift + cbase);
                v0 = fmaxf(fmaxf(v0 + bb.x, 0.f) * sc.x + sh.x, 0.f);
                v1 = fmaxf(fmaxf(v1 + bb.y, 0.f) * sc.y + sh.y, 0.f);
                v2 = fmaxf(fmaxf(v2 + bb.z, 0.f) * sc.z + sh.z, 0.f);
                v3 = fmaxf(fmaxf(v3 + bb.w, 0.f) * sc.w + sh.w, 0.f);
            }
            v0 *= d; v1 *= d; v2 *= d; v3 *= d;
            uint2 st;
            st.x = pack2(v0, v1);
            st.y = pack2(v2, v3);
            *(uint2*)(out + (long long)row * 64 + (cbase >> 1)) = st;
        }
    }
}

// ---------------- fused (pool-mm -> mm) + optional T0 side-GEMM blocks ----------------
// Blocks >= (M+63)/64 compute T0 = A @ W10 (fp32 out) -- identical FP order to old mm10p GEMM.
#define TLP 68
__global__ __launch_bounds__(256) void mm128x2_kernel(
    const u32* __restrict__ Av, const u32* __restrict__ Wa, const u32* __restrict__ Wb,
    u32* __restrict__ out, int M,
    const float* __restrict__ dis2,
    const float* __restrict__ bias1,
    const float* __restrict__ bnscale1, const float* __restrict__ bnshift1,
    const int* __restrict__ pp, const int* __restrict__ childl, int apool,
    const float* __restrict__ W10, float* __restrict__ T0out, int Mt0)
{
    __shared__ u32 WL[8192];
    __shared__ u32 TL[64 * TLP];
    int tid = threadIdx.x;
    int nmm = (M + 63) >> 6;
    if ((int)blockIdx.x >= nmm) {
        // ---- T0 side blocks: rows of Av (u32 bf16x2) @ W10[128][10] -> fp32 ----
        int rowt = ((int)blockIdx.x - nmm) * 256 + tid;
        if (rowt < Mt0) {
            const uint4* a = (const uint4*)(Av + (long long)rowt * 64);
            float acc[10] = {0, 0, 0, 0, 0, 0, 0, 0, 0, 0};
            #pragma unroll 4
            for (int i = 0; i < 16; i++) {
                uint4 av = a[i];
                int k = i * 8;
                float f[8] = { bl(av.x), bh(av.x), bl(av.y), bh(av.y),
                               bl(av.z), bh(av.z), bl(av.w), bh(av.w) };
                #pragma unroll
                for (int j = 0; j < 8; j++) {
                    #pragma unroll
                    for (int cc = 0; cc < 10; cc++)
                        acc[cc] += f[j] * W10[(k + j) * 10 + cc];
                }
            }
            #pragma unroll
            for (int cc = 0; cc < 10; cc++) T0out[(long long)rowt * 10 + cc] = acc[cc];
        }
        return;
    }
    {
        const uint4* ws4 = (const uint4*)Wa;
        uint4* wd4 = (uint4*)WL;
        #pragma unroll
        for (int it = 0; it < 8; it++) wd4[it * 256 + tid] = ws4[it * 256 + tid];
    }
    __syncthreads();

    int lane = tid & 63;
    int w = tid >> 6;
    int m = lane & 15, q = lane >> 4;
    int row = blockIdx.x * 64 + w * 16 + m;
    bool live = (row < M);

    // ---- stage 1 A fragments ----
    uint4 xb[4];
    if (live) {
        if (apool) {
            float fa[32];
            #pragma unroll
            for (int i = 0; i < 32; i++) fa[i] = 0.f;
            int e = pp[row], eE = pp[row + 1];
            for (; e < eE; e++) {
                long long cb = (long long)childl[e] * 64;
                #pragma unroll
                for (int s = 0; s < 4; s++) {
                    uint4 vv = *(const uint4*)(Av + cb + s * 16 + q * 4);
                    fa[s * 8 + 0] += bl(vv.x); fa[s * 8 + 1] += bh(vv.x);
                    fa[s * 8 + 2] += bl(vv.y); fa[s * 8 + 3] += bh(vv.y);
                    fa[s * 8 + 4] += bl(vv.z); fa[s * 8 + 5] += bh(vv.z);
                    fa[s * 8 + 6] += bl(vv.w); fa[s * 8 + 7] += bh(vv.w);
                }
            }
            #pragma unroll
            for (int s = 0; s < 4; s++) {
                xb[s].x = pack2(fa[s * 8 + 0], fa[s * 8 + 1]);
                xb[s].y = pack2(fa[s * 8 + 2], fa[s * 8 + 3]);
                xb[s].z = pack2(fa[s * 8 + 4], fa[s * 8 + 5]);
                xb[s].w = pack2(fa[s * 8 + 6], fa[s * 8 + 7]);
            }
        } else {
            #pragma unroll
            for (int s = 0; s < 4; s++)
                xb[s] = *(const uint4*)(Av + (long long)row * 64 + s * 16 + q * 4);
        }
    } else {
        xb[0] = xb[1] = xb[2] = xb[3] = make_uint4(0u, 0u, 0u, 0u);
    }

    u32* tl = TL + (w * 16 + m) * TLP;

    #pragma unroll
    for (int t = 0; t < 8; t++) {
        f32x4 acc = {0.f, 0.f, 0.f, 0.f};
        #pragma unroll
        for (int s = 0; s < 4; s++) {
            uint4 wa4 = *(const uint4*)&WL[((t * 4 + s) * 64 + lane) * 4];
            acc = __builtin_amdgcn_mfma_f32_16x16x32_bf16(asbf(wa4), asbf(xb[s]), acc, 0, 0, 0);
        }
        int cbase = t * 16 + q * 4;
        float4 bb = *(const float4*)(bias1 + cbase);
        float4 sc = *(const float4*)(bnscale1 + cbase);
        float4 sh = *(const float4*)(bnshift1 + cbase);
        float v0 = fmaxf(fmaxf(acc[0] + bb.x, 0.f) * sc.x + sh.x, 0.f);
        float v1 = fmaxf(fmaxf(acc[1] + bb.y, 0.f) * sc.y + sh.y, 0.f);
        float v2 = fmaxf(fmaxf(acc[2] + bb.z, 0.f) * sc.z + sh.z, 0.f);
        float v3 = fmaxf(fmaxf(acc[3] + bb.w, 0.f) * sc.w + sh.w, 0.f);
        uint2 st;
        st.x = pack2(v0, v1);
        st.y = pack2(v2, v3);
        *(uint2*)&tl[t * 8 + q * 2] = st;
    }
    __syncthreads();
    {
        const uint4* ws4 = (const uint4*)Wb;
        uint4* wd4 = (uint4*)WL;
        #pragma unroll
        for (int it = 0; it < 8; it++) wd4[it * 256 + tid] = ws4[it * 256 + tid];
    }
    __syncthreads();

    // ---- stage 2 ----
    #pragma unroll
    for (int s = 0; s < 4; s++)
        xb[s] = *(const uint4*)&tl[s * 16 + q * 4];
    float d = 1.0f;
    if (dis2 && live) d = dis2[row];

    #pragma unroll
    for (int t = 0; t < 8; t++) {
        f32x4 acc = {0.f, 0.f, 0.f, 0.f};
        #pragma unroll
        for (int s = 0; s < 4; s++) {
            uint4 wa4 = *(const uint4*)&WL[((t * 4 + s) * 64 + lane) * 4];
            acc = __builtin_amdgcn_mfma_f32_16x16x32_bf16(asbf(wa4), asbf(xb[s]), acc, 0, 0, 0);
        }
        if (live) {
            int cbase = t * 16 + q * 4;
            float v0 = acc[0] * d, v1 = acc[1] * d, v2 = acc[2] * d, v3 = acc[3] * d;
            uint2 st;
            st.x = pack2(v0, v1);
            st.y = pack2(v2, v3);
            *(uint2*)(out + (long long)row * 64 + (cbase >> 1)) = st;
        }
    }
}

// ---------------- fused up1: (pool-mm 128x128 w/ bias+bn+relu) -> mm K=128,N=10 ----------------
__global__ __launch_bounds__(256) void mm128_mm10_kernel(
    const u32* __restrict__ Av, const u32* __restrict__ Wp,
    const float* __restrict__ W10,
    float* __restrict__ out10, int M,
    const float* __restrict__ bias1,
    const float* __restrict__ bnscale1, const float* __restrict__ bnshift1)
{
    __shared__ u32 WL[8192];
    __shared__ u32 TL[64 * TLP];
    __shared__ float Ws[128 * 10];
    int tid = threadIdx.x;
    {
        const uint4* ws4 = (const uint4*)Wp;
        uint4* wd4 = (uint4*)WL;
        #pragma unroll
        for (int it = 0; it < 8; it++) wd4[it * 256 + tid] = ws4[it * 256 + tid];
    }
    for (int i = tid; i < 1280; i += 256) Ws[i] = W10[i];
    __syncthreads();

    int lane = tid & 63;
    int w = tid >> 6;
    int m = lane & 15, q = lane >> 4;
    int row = blockIdx.x * 64 + w * 16 + m;
    bool live = (row < M);

    uint4 xb[4];
    if (live) {
        #pragma unroll
        for (int s = 0; s < 4; s++)
            xb[s] = *(const uint4*)(Av + (long long)row * 64 + s * 16 + q * 4);
    } else {
        xb[0] = xb[1] = xb[2] = xb[3] = make_uint4(0u, 0u, 0u, 0u);
    }

    u32* tl = TL + (w * 16 + m) * TLP;

    #pragma unroll
    for (int t = 0; t < 8; t++) {
        f32x4 acc = {0.f, 0.f, 0.f, 0.f};
        #pragma unroll
        for (int s = 0; s < 4; s++) {
            uint4 wa4 = *(const uint4*)&WL[((t * 4 + s) * 64 + lane) * 4];
            acc = __builtin_amdgcn_mfma_f32_16x16x32_bf16(asbf(wa4), asbf(xb[s]), acc, 0, 0, 0);
        }
        int cbase = t * 16 + q * 4;
        float4 bb = *(const float4*)(bias1 + cbase);
        float4 sc = *(const float4*)(bnscale1 + cbase);
        float4 sh = *(const float4*)(bnshift1 + cbase);
        float v0 = fmaxf(fmaxf(acc[0] + bb.x, 0.f) * sc.x + sh.x, 0.f);
        float v1 = fmaxf(fmaxf(acc[1] + bb.y, 0.f) * sc.y + sh.y, 0.f);
        float v2 = fmaxf(fmaxf(acc[2] + bb.z, 0.f) * sc.z + sh.z, 0.f);
        float v3 = fmaxf(fmaxf(acc[3] + bb.w, 0.f) * sc.w + sh.w, 0.f);
        uint2 st;
        st.x = pack2(v0, v1);
        st.y = pack2(v2, v3);
        *(uint2*)&tl[t * 8 + q * 2] = st;
    }
    __syncthreads();

    // stage 2: 64 rows x 10 cols, dot over 128 (ascending k)
    int base = blockIdx.x * 64;
    for (int slot = tid; slot < 640; slot += 256) {
        int r = slot / 10, cc = slot % 10;
        if (base + r < M) {
            const u32* tr = &TL[r * TLP];
            float acc = 0.f;
            #pragma unroll
            for (int k2 = 0; k2 < 64; k2++) {
                u32 p = tr[k2];
                acc += bl(p) * Ws[(2 * k2) * 10 + cc];
                acc += bh(p) * Ws[(2 * k2 + 1) * 10 + cc];
            }
            out10[(long long)(base + r) * 10 + cc] = acc;
        }
    }
}

// ---------------- gcn4 epilogue: T0 + W1b[parent] add, dis scale, bf16 pack ----------------
__global__ __launch_bounds__(256) void mm10p2_kernel(
    const float* __restrict__ T0, const float* __restrict__ gsrc,
    const int* __restrict__ gidx, const float* __restrict__ dis,
    u32* __restrict__ outp, int M)
{
    int row = blockIdx.x * 256 + threadIdx.x;
    if (row >= M) return;
    float d = dis[row];
    const float* t = T0 + (long long)row * 10;
    const float* g = gsrc + (long long)gidx[row] * 10;
    long long base = (long long)row * 8;
    #pragma unroll
    for (int j = 0; j < 5; j++) {
        float v0 = (t[2 * j] + g[2 * j]) * d;
        float v1 = (t[2 * j + 1] + g[2 * j + 1]) * d;
        outp[base + j] = pack2(v0, v1);
    }
}

// ---------------- launcher ----------------

extern "C" void kernel_launch(void* const* d_in, const int* in_sizes, int n_in,
                              void* d_out, int out_size, void* d_ws, size_t ws_size,
                              hipStream_t stream) {
    const float* x       = (const float*)d_in[0];
    const int*   ei0     = (const int*)d_in[1];
    const int*   ei1     = (const int*)d_in[2];
    const int*   ei2     = (const int*)d_in[3];
    const int*   parent1 = (const int*)d_in[4];
    const int*   parent2 = (const int*)d_in[5];
    const float* W0 = (const float*)d_in[6];
    const float* b0 = (const float*)d_in[7];
    const float* W1 = (const float*)d_in[8];
    const float* b1 = (const float*)d_in[9];
    const float* W2 = (const float*)d_in[10];
    const float* b2 = (const float*)d_in[11];
    const float* W3 = (const float*)d_in[12];
    const float* b3 = (const float*)d_in[13];
    const float* W4 = (const float*)d_in[14];
    const float* b4 = (const float*)d_in[15];
    const float* pW = (const float*)d_in[16];
    const float* pb = (const float*)d_in[17];
    const float* pg = (const float*)d_in[18];
    const float* pbeta = (const float*)d_in[19];
    const float* pmean = (const float*)d_in[20];
    const float* pvar  = (const float*)d_in[21];
    float* out = (float*)d_out;

    char* ws = (char*)d_ws;
    size_t off = 0;
    auto alloc = [&](size_t nbytes) -> char* {
        char* p = ws + off;
        off += ((nbytes + 255) / 256) * 256;
        return p;
    };
    float* dis0 = (float*)alloc(N0 * 4);
    float* dis1 = (float*)alloc(N1 * 4);
    float* dis2 = (float*)alloc(N2 * 4);
    float* bnscale = (float*)alloc(4 * HDIM * 4);
    float* bnshift = (float*)alloc(4 * HDIM * 4);
    float* W1b = (float*)alloc((size_t)N1 * 10 * 4);
    float* T0  = (float*)alloc((size_t)N0 * 10 * 4);
    u32* Y   = (u32*)alloc((size_t)N0 * 64 * 4);
    u32* H0  = (u32*)alloc((size_t)N0 * 64 * 4);
    u32* H1  = (u32*)alloc((size_t)N1 * 64 * 4);
    u32* HU1 = (u32*)alloc((size_t)N1 * 64 * 4);
    u32* H2  = (u32*)alloc((size_t)N2 * 64 * 4);
    u32* V2  = (u32*)alloc((size_t)N2 * 64 * 4);
    u32* Y4p = (u32*)alloc((size_t)N0 * 8 * 4);
    u32* Wpk = (u32*)alloc((size_t)NWMAT * 8192 * 4);
    int* rpAll = (int*)alloc((size_t)(OFFT + 1) * 4);
    int* srcU  = (int*)alloc((size_t)S4 * 4);
    int* blockHist = (int*)alloc((size_t)BH_N * 4);
    int* OfsAbs    = (int*)alloc((size_t)(BH_N + 1) * 4);
    u32* binPair   = (u32*)alloc((size_t)S4 * 4);
    int* bsum   = (int*)alloc(NBLK2 * 4);
    int* totalb = (int*)alloc(4);

    const int B = 256;
    auto G = [](long long t) { return (unsigned)((t + 255) / 256); };
    auto G64 = [](long long m) { return (unsigned)((m + 63) / 64); };

    // ---- CSR build (+ W prepack hidden in binhist grid) ----
    binhist_kernel<<<NBA + NWMAT, B, 0, stream>>>(
        ei0 + E0C, ei1 + E1C, ei2 + E2C, parent1, parent2, blockHist,
        W0, W1, W2, W3, pW, Wpk);
    scan_k1<<<NBLK2, B, 0, stream>>>(blockHist, bsum, BH_N);
    scan_k2<<<1, B, 0, stream>>>(bsum, totalb, NBLK2, pg, pbeta, pmean, pvar, bnscale, bnshift);
    scan_k3<<<NBLK2, B, 0, stream>>>(blockHist, bsum, totalb, OfsAbs, BH_N);
    binfill_kernel<<<NBA, B, 0, stream>>>(
        ei0, ei0 + E0C, ei1, ei1 + E1C, ei2, ei2 + E2C, parent1, parent2, OfsAbs, binPair);
    bucket_build_kernel<<<NBUCK, 1024, 0, stream>>>(
        binPair, OfsAbs, rpAll, srcU, dis0, dis1, dis2);

    // ---- gcn0 ----
    mm128_kernel<<<G64(N0), B, 0, stream>>>(
        x, Wpk + 0 * 8192, Y, N0, dis0, nullptr, nullptr, nullptr, nullptr, nullptr, 0, 1,
        nullptr, nullptr, 0);
    gather128_kernel<<<G((long long)N0 * 64), B, 0, stream>>>(rpAll + OFF0, srcU, Y, dis0, b0, H0, N0);

    // ---- pool1 + gcn1 (fused) + T0 = H0 @ W4lo side blocks ----
    mm128x2_kernel<<<G64(N1) + G(N0), B, 0, stream>>>(
        H0, Wpk + 5 * 8192, Wpk + 1 * 8192, Y, N1, dis1,
        pb, bnscale, bnshift, rpAll + OFF3, srcU, 1,
        W4 + 128 * 10, T0, N0);
    gather128_kernel<<<G((long long)N1 * 64), B, 0, stream>>>(rpAll + OFF1, srcU, Y, dis1, b1, H1, N1);

    // ---- pool2 + gcn2 (fused) ----
    mm128x2_kernel<<<G64(N2), B, 0, stream>>>(
        H1, Wpk + 6 * 8192, Wpk + 2 * 8192, Y, N2, dis2,
        pb + 128, bnscale + 128, bnshift + 128, rpAll + OFF4, srcU, 1,
        nullptr, nullptr, 0);
    gather128_kernel<<<G((long long)N2 * 64), B, 0, stream>>>(rpAll + OFF2, srcU, Y, dis2, b2, H2, N2);

    // ---- up level 2 (fused pool + mm) ----
    mm128x2_kernel<<<G64(N2), B, 0, stream>>>(
        H2, Wpk + 7 * 8192, Wpk + 3 * 8192, V2, N2, nullptr,
        pb + 256, bnscale + 256, bnshift + 256, nullptr, nullptr, 0,
        nullptr, nullptr, 0);

    // ---- gcn3 ----
    mm128_kernel<<<G64(N1), B, 0, stream>>>(
        H1, Wpk + 4 * 8192, Y, N1, dis1, V2, parent2, nullptr, nullptr, nullptr, 0, 0,
        nullptr, nullptr, 0);
    gather128_kernel<<<G((long long)N1 * 64), B, 0, stream>>>(rpAll + OFF1, srcU, Y, dis1, b3, HU1, N1);

    // ---- up level 1 (fused pool-mm + N=10 matmul) ----
    mm128_mm10_kernel<<<G64(N1), B, 0, stream>>>(
        HU1, Wpk + 8 * 8192, W4, W1b, N1, pb + 384, bnscale + 384, bnshift + 384);

    // ---- gcn4 ----
    mm10p2_kernel<<<G(N0), B, 0, stream>>>(T0, W1b, parent1, dis0, Y4p, N0);
    gather10_lsm_kernel<<<G(N0), B, 0, stream>>>(rpAll + OFF0, srcU, Y4p, dis0, b4, out, N0);
}